// Round 4
// baseline (427.406 us; speedup 1.0000x reference)
//
#include <hip/hip_runtime.h>
#include <hip/hip_bf16.h>

#define F 64          // DIN == DOUT == 64
#define BK 128        // dst nodes per coarse bucket
#define KBUCKET 782   // ceil(100000/128); recomputed at runtime, must be <= 1024

// ---------------- h = x @ W  (output bf16) ----------------
__global__ void gemm_kernel(const float* __restrict__ x, const float* __restrict__ W,
                            __hip_bfloat16* __restrict__ h, int n) {
    __shared__ float Ws[F * F];
    int tid = threadIdx.x;
    for (int i = tid; i < F * F; i += 256) Ws[i] = W[i];
    __syncthreads();
    int c = tid & 63;
    int wv = __builtin_amdgcn_readfirstlane(tid >> 6);  // wave id 0..3
    int base = blockIdx.x * 64 + wv * 16;
    for (int it = 0; it < 4; ++it) {
        int r0 = base + it * 4;
        if (r0 + 3 < n) {
            const float* x0 = x + (size_t)r0 * F;
            float a0 = 0.f, a1 = 0.f, a2 = 0.f, a3 = 0.f;
#pragma unroll
            for (int k = 0; k < F; ++k) {
                float w = Ws[k * F + c];
                a0 += x0[k] * w;
                a1 += x0[F + k] * w;
                a2 += x0[2 * F + k] * w;
                a3 += x0[3 * F + k] * w;
            }
            h[(size_t)r0 * F + c]       = __float2bfloat16(a0);
            h[(size_t)(r0 + 1) * F + c] = __float2bfloat16(a1);
            h[(size_t)(r0 + 2) * F + c] = __float2bfloat16(a2);
            h[(size_t)(r0 + 3) * F + c] = __float2bfloat16(a3);
        } else {
            for (int j = 0; j < 4; ++j) {
                int r = r0 + j;
                if (r < n) {
                    const float* xr = x + (size_t)r * F;
                    float acc = 0.f;
#pragma unroll
                    for (int k = 0; k < F; ++k) acc += xr[k] * Ws[k * F + c];
                    h[(size_t)r * F + c] = __float2bfloat16(acc);
                }
            }
        }
    }
}

// ---------------- coarse histogram of col>>7 (LDS-aggregated) ----------------
__global__ void hist_kernel(const int* __restrict__ col, int* __restrict__ bcnt,
                            int e, int K) {
    __shared__ int lh[1024];
    int tid = threadIdx.x;
    for (int i = tid; i < K; i += 256) lh[i] = 0;
    __syncthreads();
    int nv = e >> 2;
    const int4* col4 = (const int4*)col;
    int stride = gridDim.x * 256;
    for (int v = blockIdx.x * 256 + tid; v < nv; v += stride) {
        int4 cs = col4[v];
        atomicAdd(&lh[cs.x >> 7], 1);
        atomicAdd(&lh[cs.y >> 7], 1);
        atomicAdd(&lh[cs.z >> 7], 1);
        atomicAdd(&lh[cs.w >> 7], 1);
    }
    if (blockIdx.x == 0 && tid == 0) {
        for (int i = nv << 2; i < e; ++i) atomicAdd(&bcnt[col[i] >> 7], 1);
    }
    __syncthreads();
    for (int i = tid; i < K; i += 256) {
        int v = lh[i];
        if (v) atomicAdd(&bcnt[i], v);
    }
}

// ---------------- single-block exclusive scan of bucket counts ----------------
__global__ void bscan_kernel(const int* __restrict__ bcnt, int* __restrict__ bstart,
                             int* __restrict__ bcursor, int K) {
    __shared__ int tmp[1024];
    int tid = threadIdx.x;
    int v = (tid < K) ? bcnt[tid] : 0;
    tmp[tid] = v;
    __syncthreads();
    for (int off = 1; off < 1024; off <<= 1) {
        int t = (tid >= off) ? tmp[tid - off] : 0;
        __syncthreads();
        tmp[tid] += t;
        __syncthreads();
    }
    if (tid < K) {
        int ex = tmp[tid] - v;
        bstart[tid] = ex;
        bcursor[tid] = ex;
        if (tid == K - 1) bstart[K] = tmp[tid];  // total == e
    }
}

// ---------------- passA: append packed (src<<7 | dst&127) to coarse bucket ----------------
__global__ void passA_kernel(const int* __restrict__ row, const int* __restrict__ col,
                             int* __restrict__ bcursor, unsigned* __restrict__ bin, int e) {
    int i4 = (blockIdx.x * 256 + threadIdx.x) * 4;
    if (i4 + 3 < e) {
        int4 rs = *(const int4*)(row + i4);
        int4 cs = *(const int4*)(col + i4);
        int p0 = atomicAdd(&bcursor[cs.x >> 7], 1);
        int p1 = atomicAdd(&bcursor[cs.y >> 7], 1);
        int p2 = atomicAdd(&bcursor[cs.z >> 7], 1);
        int p3 = atomicAdd(&bcursor[cs.w >> 7], 1);
        bin[p0] = ((unsigned)rs.x << 7) | ((unsigned)cs.x & 127u);
        bin[p1] = ((unsigned)rs.y << 7) | ((unsigned)cs.y & 127u);
        bin[p2] = ((unsigned)rs.z << 7) | ((unsigned)cs.z & 127u);
        bin[p3] = ((unsigned)rs.w << 7) | ((unsigned)cs.w & 127u);
    } else {
        for (int i = i4; i < e; ++i) {
            int p = atomicAdd(&bcursor[col[i] >> 7], 1);
            bin[p] = ((unsigned)row[i] << 7) | ((unsigned)col[i] & 127u);
        }
    }
}

// ---------------- passB: per-bucket exact sort + metadata + h scale ----------------
__global__ void passB_kernel(const unsigned* __restrict__ bin, const int* __restrict__ bstart,
                             int* __restrict__ csr, int2* __restrict__ rng,
                             float* __restrict__ dinv, __hip_bfloat16* __restrict__ h,
                             int n) {
    __shared__ int lcnt[BK];
    __shared__ int lcur[BK];
    __shared__ int sc[BK];
    __shared__ float sdinv[BK];
    int tid = threadIdx.x;
    int b = blockIdx.x;
    int base = b << 7;
    if (tid < BK) lcnt[tid] = 0;
    __syncthreads();
    int s = bstart[b];
    int e2 = bstart[b + 1];
    // exact histogram
    for (int p = s + tid; p < e2; p += 256) atomicAdd(&lcnt[bin[p] & 127u], 1);
    __syncthreads();
    // inclusive scan of lcnt over BK entries
    if (tid < BK) sc[tid] = lcnt[tid];
    __syncthreads();
    for (int off = 1; off < BK; off <<= 1) {
        int t = (tid < BK && tid >= off) ? sc[tid - off] : 0;
        __syncthreads();
        if (tid < BK) sc[tid] += t;
        __syncthreads();
    }
    if (tid < BK) {
        int cnt = lcnt[tid];
        int lstart = sc[tid] - cnt;  // exclusive
        lcur[tid] = lstart;
        int node = base + tid;
        if (node < n) {
            int gs = s + lstart;
            rng[node] = make_int2(gs, gs + cnt);
            float di = rsqrtf((float)(cnt + 1));
            dinv[node] = di;
            sdinv[tid] = di;
        }
    }
    __syncthreads();
    // scatter srcs into final CSR (writes stay in this bucket's ~5KB window)
    for (int p = s + tid; p < e2; p += 256) {
        unsigned u = bin[p];
        int ld = (int)(u & 127u);
        int src = (int)(u >> 7);
        int pos = s + atomicAdd(&lcur[ld], 1);
        csr[pos] = src;
    }
    // scale this bucket's h rows in place: h[node] *= dinv[node]
    int lim = BK * F;
    for (int idx = tid; idx < lim; idx += 256) {
        int node = base + (idx >> 6);
        if (node < n) {
            float di = sdinv[idx >> 6];
            size_t off = (size_t)node * F + (idx & 63);
            h[off] = __float2bfloat16(di * __bfloat162float(h[off]));
        }
    }
}

// ---------------- gather: one wave per node, lane = channel ----------------
// h rows are pre-scaled by dinv[src]; self-loop term is h[i] itself.
__global__ void gather_kernel(const __hip_bfloat16* __restrict__ h,
                              const int* __restrict__ csr,
                              const int2* __restrict__ rng,
                              const float* __restrict__ dinv, const float* __restrict__ b,
                              float* __restrict__ out, int n) {
    int gid = blockIdx.x * blockDim.x + threadIdx.x;
    int i = gid >> 6;
    int c = gid & 63;
    if (i >= n) return;
    float di = dinv[i];
    int2 r = rng[i];
    int p = r.x, pend = r.y;
    float acc = __bfloat162float(h[(size_t)i * F + c]);  // self-loop (pre-scaled)
    for (; p + 4 <= pend; p += 4) {
        int s0 = csr[p];
        int s1 = csr[p + 1];
        int s2 = csr[p + 2];
        int s3 = csr[p + 3];
        float h0 = __bfloat162float(h[(size_t)s0 * F + c]);
        float h1 = __bfloat162float(h[(size_t)s1 * F + c]);
        float h2 = __bfloat162float(h[(size_t)s2 * F + c]);
        float h3 = __bfloat162float(h[(size_t)s3 * F + c]);
        acc += h0 + h1 + h2 + h3;
    }
    for (; p < pend; ++p) acc += __bfloat162float(h[(size_t)csr[p] * F + c]);
    float v = di * acc + b[c];
    out[(size_t)i * F + c] = v > 0.f ? v : 0.f;
}

extern "C" void kernel_launch(void* const* d_in, const int* in_sizes, int n_in,
                              void* d_out, int out_size, void* d_ws, size_t ws_size,
                              hipStream_t stream) {
    const float* x = (const float*)d_in[0];
    const int* ei  = (const int*)d_in[1];
    const float* W = (const float*)d_in[2];
    const float* b = (const float*)d_in[3];
    float* out = (float*)d_out;

    int n = in_sizes[0] / F;   // 100000
    int e = in_sizes[1] / 2;   // 1000000
    const int* row = ei;       // source
    const int* col = ei + e;   // target
    int K = (n + BK - 1) / BK; // 782 (<= 1024 required)

    // workspace layout (~22 MB)
    __hip_bfloat16* h = (__hip_bfloat16*)d_ws;                 // n*F bf16   12.8 MB
    unsigned* bin = (unsigned*)((char*)d_ws + (size_t)n * F * 2); // e          4 MB
    int* csr      = (int*)(bin + e);                           // e            4 MB
    int2* rng     = (int2*)(csr + e);                          // n            0.8 MB
    float* dinv   = (float*)(rng + n);                         // n            0.4 MB
    int* bcnt     = (int*)(dinv + n);                          // K
    int* bstart   = bcnt + 1024;                               // K+1
    int* bcursor  = bstart + 1025;                             // K

    // 1. h = x @ W (bf16), independent of the CSR build
    gemm_kernel<<<(n + 63) / 64, 256, 0, stream>>>(x, W, h, n);

    // 2. coarse histogram
    hipMemsetAsync(bcnt, 0, 1024 * sizeof(int), stream);
    hist_kernel<<<64, 256, 0, stream>>>(col, bcnt, e, K);

    // 3. scan bucket counts
    bscan_kernel<<<1, 1024, 0, stream>>>(bcnt, bstart, bcursor, K);

    // 4. passA: bin edges by coarse bucket (packed 4B entries)
    passA_kernel<<<(e / 4 + 255) / 256, 256, 0, stream>>>(row, col, bcursor, bin, e);

    // 5. passB: exact per-dst sort, rng/dinv, h *= dinv in place
    passB_kernel<<<K, 256, 0, stream>>>(bin, bstart, csr, rng, dinv, h, n);

    // 6. gather + self-loop + bias + relu
    gather_kernel<<<((size_t)n * F + 255) / 256, 256, 0, stream>>>(
        h, csr, rng, dinv, b, out, n);
}

// Round 5
// 209.222 us; speedup vs baseline: 2.0428x; 2.0428x over previous
//
#include <hip/hip_runtime.h>
#include <hip/hip_bf16.h>

#define F 64          // DIN == DOUT == 64
#define BK 128        // dst nodes per coarse bucket
#define PA_BLOCKS 256 // passA grid: block-aggregated frontier reservation

// ---------------- h = x @ W  (output bf16) ----------------
__global__ void gemm_kernel(const float* __restrict__ x, const float* __restrict__ W,
                            __hip_bfloat16* __restrict__ h, int n) {
    __shared__ float Ws[F * F];
    int tid = threadIdx.x;
    for (int i = tid; i < F * F; i += 256) Ws[i] = W[i];
    __syncthreads();
    int c = tid & 63;
    int wv = __builtin_amdgcn_readfirstlane(tid >> 6);  // wave id 0..3
    int base = blockIdx.x * 64 + wv * 16;
    for (int it = 0; it < 4; ++it) {
        int r0 = base + it * 4;
        if (r0 + 3 < n) {
            const float* x0 = x + (size_t)r0 * F;
            float a0 = 0.f, a1 = 0.f, a2 = 0.f, a3 = 0.f;
#pragma unroll
            for (int k = 0; k < F; ++k) {
                float w = Ws[k * F + c];
                a0 += x0[k] * w;
                a1 += x0[F + k] * w;
                a2 += x0[2 * F + k] * w;
                a3 += x0[3 * F + k] * w;
            }
            h[(size_t)r0 * F + c]       = __float2bfloat16(a0);
            h[(size_t)(r0 + 1) * F + c] = __float2bfloat16(a1);
            h[(size_t)(r0 + 2) * F + c] = __float2bfloat16(a2);
            h[(size_t)(r0 + 3) * F + c] = __float2bfloat16(a3);
        } else {
            for (int j = 0; j < 4; ++j) {
                int r = r0 + j;
                if (r < n) {
                    const float* xr = x + (size_t)r * F;
                    float acc = 0.f;
#pragma unroll
                    for (int k = 0; k < F; ++k) acc += xr[k] * Ws[k * F + c];
                    h[(size_t)r * F + c] = __float2bfloat16(acc);
                }
            }
        }
    }
}

// ---------------- coarse histogram of col>>7 (LDS-aggregated) ----------------
__global__ void hist_kernel(const int* __restrict__ col, int* __restrict__ bcnt,
                            int e, int K) {
    __shared__ int lh[1024];
    int tid = threadIdx.x;
    for (int i = tid; i < K; i += 256) lh[i] = 0;
    __syncthreads();
    int nv = e >> 2;
    const int4* col4 = (const int4*)col;
    int stride = gridDim.x * 256;
    for (int v = blockIdx.x * 256 + tid; v < nv; v += stride) {
        int4 cs = col4[v];
        atomicAdd(&lh[cs.x >> 7], 1);
        atomicAdd(&lh[cs.y >> 7], 1);
        atomicAdd(&lh[cs.z >> 7], 1);
        atomicAdd(&lh[cs.w >> 7], 1);
    }
    if (blockIdx.x == 0 && tid == 0) {
        for (int i = nv << 2; i < e; ++i) atomicAdd(&bcnt[col[i] >> 7], 1);
    }
    __syncthreads();
    for (int i = tid; i < K; i += 256) {
        int v = lh[i];
        if (v) atomicAdd(&bcnt[i], v);
    }
}

// ---------------- single-block exclusive scan of bucket counts ----------------
__global__ void bscan_kernel(const int* __restrict__ bcnt, int* __restrict__ bstart,
                             int* __restrict__ bcursor, int K) {
    __shared__ int tmp[1024];
    int tid = threadIdx.x;
    int v = (tid < K) ? bcnt[tid] : 0;
    tmp[tid] = v;
    __syncthreads();
    for (int off = 1; off < 1024; off <<= 1) {
        int t = (tid >= off) ? tmp[tid - off] : 0;
        __syncthreads();
        tmp[tid] += t;
        __syncthreads();
    }
    if (tid < K) {
        int ex = tmp[tid] - v;
        bstart[tid] = ex;
        bcursor[tid] = ex;
        if (tid == K - 1) bstart[K] = tmp[tid];  // total == e
    }
}

// ---------------- passA: block-aggregated binning ----------------
// Each block: LDS histogram of its edge chunk -> ONE global atomicAdd per
// touched bucket to reserve a span -> place via LDS cursors. Global atomic
// count drops from 1M (1 per edge) to <=200k (1 per block-bucket), removing
// the same-address serialization that cost 238 us in round 4.
__global__ void passA_kernel(const int* __restrict__ row, const int* __restrict__ col,
                             int* __restrict__ bcursor, unsigned* __restrict__ bin,
                             int e, int K, int chunk) {
    __shared__ int lh[1024];     // local histogram, then local cursor
    __shared__ int lbase[1024];  // reserved global base per bucket
    int tid = threadIdx.x;
    int s = blockIdx.x * chunk;
    int lim = s + chunk;
    if (lim > e) lim = e;
    for (int i = tid; i < K; i += 256) lh[i] = 0;
    __syncthreads();
    // pass 1: local histogram
    for (int i = s + tid; i < lim; i += 256) atomicAdd(&lh[col[i] >> 7], 1);
    __syncthreads();
    // reserve global spans (one atomic per touched bucket)
    for (int i = tid; i < K; i += 256) {
        int c = lh[i];
        lbase[i] = c ? atomicAdd(&bcursor[i], c) : 0;
        lh[i] = 0;  // reuse as local cursor
    }
    __syncthreads();
    // pass 2: place packed entries
    for (int i = s + tid; i < lim; i += 256) {
        int d = col[i];
        int bkt = d >> 7;
        int off = atomicAdd(&lh[bkt], 1);
        bin[lbase[bkt] + off] = ((unsigned)row[i] << 7) | ((unsigned)d & 127u);
    }
}

// ---------------- passB: per-bucket exact sort + metadata + h scale ----------------
__global__ void passB_kernel(const unsigned* __restrict__ bin, const int* __restrict__ bstart,
                             int* __restrict__ csr, int2* __restrict__ rng,
                             float* __restrict__ dinv, __hip_bfloat16* __restrict__ h,
                             int n) {
    __shared__ int lcnt[BK];
    __shared__ int lcur[BK];
    __shared__ int sc[BK];
    __shared__ float sdinv[BK];
    int tid = threadIdx.x;
    int b = blockIdx.x;
    int base = b << 7;
    if (tid < BK) lcnt[tid] = 0;
    __syncthreads();
    int s = bstart[b];
    int e2 = bstart[b + 1];
    // exact histogram
    for (int p = s + tid; p < e2; p += 256) atomicAdd(&lcnt[bin[p] & 127u], 1);
    __syncthreads();
    // inclusive scan of lcnt over BK entries
    if (tid < BK) sc[tid] = lcnt[tid];
    __syncthreads();
    for (int off = 1; off < BK; off <<= 1) {
        int t = (tid < BK && tid >= off) ? sc[tid - off] : 0;
        __syncthreads();
        if (tid < BK) sc[tid] += t;
        __syncthreads();
    }
    if (tid < BK) {
        int cnt = lcnt[tid];
        int lstart = sc[tid] - cnt;  // exclusive
        lcur[tid] = lstart;
        int node = base + tid;
        if (node < n) {
            int gs = s + lstart;
            rng[node] = make_int2(gs, gs + cnt);
            float di = rsqrtf((float)(cnt + 1));
            dinv[node] = di;
            sdinv[tid] = di;
        }
    }
    __syncthreads();
    // scatter srcs into final CSR (writes stay in this bucket's ~5KB window)
    for (int p = s + tid; p < e2; p += 256) {
        unsigned u = bin[p];
        int ld = (int)(u & 127u);
        int src = (int)(u >> 7);
        int pos = s + atomicAdd(&lcur[ld], 1);
        csr[pos] = src;
    }
    // scale this bucket's h rows in place: h[node] *= dinv[node]
    int lim = BK * F;
    for (int idx = tid; idx < lim; idx += 256) {
        int node = base + (idx >> 6);
        if (node < n) {
            float di = sdinv[idx >> 6];
            size_t off = (size_t)node * F + (idx & 63);
            h[off] = __float2bfloat16(di * __bfloat162float(h[off]));
        }
    }
}

// ---------------- gather: one wave per node, lane = channel ----------------
// h rows are pre-scaled by dinv[src]; self-loop term is h[i] itself.
__global__ void gather_kernel(const __hip_bfloat16* __restrict__ h,
                              const int* __restrict__ csr,
                              const int2* __restrict__ rng,
                              const float* __restrict__ dinv, const float* __restrict__ b,
                              float* __restrict__ out, int n) {
    int gid = blockIdx.x * blockDim.x + threadIdx.x;
    int i = gid >> 6;
    int c = gid & 63;
    if (i >= n) return;
    float di = dinv[i];
    int2 r = rng[i];
    int p = r.x, pend = r.y;
    float acc = __bfloat162float(h[(size_t)i * F + c]);  // self-loop (pre-scaled)
    for (; p + 4 <= pend; p += 4) {
        int s0 = csr[p];
        int s1 = csr[p + 1];
        int s2 = csr[p + 2];
        int s3 = csr[p + 3];
        float h0 = __bfloat162float(h[(size_t)s0 * F + c]);
        float h1 = __bfloat162float(h[(size_t)s1 * F + c]);
        float h2 = __bfloat162float(h[(size_t)s2 * F + c]);
        float h3 = __bfloat162float(h[(size_t)s3 * F + c]);
        acc += h0 + h1 + h2 + h3;
    }
    for (; p < pend; ++p) acc += __bfloat162float(h[(size_t)csr[p] * F + c]);
    float v = di * acc + b[c];
    out[(size_t)i * F + c] = v > 0.f ? v : 0.f;
}

extern "C" void kernel_launch(void* const* d_in, const int* in_sizes, int n_in,
                              void* d_out, int out_size, void* d_ws, size_t ws_size,
                              hipStream_t stream) {
    const float* x = (const float*)d_in[0];
    const int* ei  = (const int*)d_in[1];
    const float* W = (const float*)d_in[2];
    const float* b = (const float*)d_in[3];
    float* out = (float*)d_out;

    int n = in_sizes[0] / F;   // 100000
    int e = in_sizes[1] / 2;   // 1000000
    const int* row = ei;       // source
    const int* col = ei + e;   // target
    int K = (n + BK - 1) / BK; // 782 (<= 1024 required)

    // workspace layout (~22 MB)
    __hip_bfloat16* h = (__hip_bfloat16*)d_ws;                 // n*F bf16   12.8 MB
    unsigned* bin = (unsigned*)((char*)d_ws + (size_t)n * F * 2); // e          4 MB
    int* csr      = (int*)(bin + e);                           // e            4 MB
    int2* rng     = (int2*)(csr + e);                          // n            0.8 MB
    float* dinv   = (float*)(rng + n);                         // n            0.4 MB
    int* bcnt     = (int*)(dinv + n);                          // K
    int* bstart   = bcnt + 1024;                               // K+1
    int* bcursor  = bstart + 1025;                             // K

    // 1. h = x @ W (bf16), independent of the CSR build
    gemm_kernel<<<(n + 63) / 64, 256, 0, stream>>>(x, W, h, n);

    // 2. coarse histogram
    hipMemsetAsync(bcnt, 0, 1024 * sizeof(int), stream);
    hist_kernel<<<64, 256, 0, stream>>>(col, bcnt, e, K);

    // 3. scan bucket counts
    bscan_kernel<<<1, 1024, 0, stream>>>(bcnt, bstart, bcursor, K);

    // 4. passA: block-aggregated binning (packed 4B entries)
    int chunk = (e + PA_BLOCKS - 1) / PA_BLOCKS;
    passA_kernel<<<PA_BLOCKS, 256, 0, stream>>>(row, col, bcursor, bin, e, K, chunk);

    // 5. passB: exact per-dst sort, rng/dinv, h *= dinv in place
    passB_kernel<<<K, 256, 0, stream>>>(bin, bstart, csr, rng, dinv, h, n);

    // 6. gather + self-loop + bias + relu
    gather_kernel<<<((size_t)n * F + 255) / 256, 256, 0, stream>>>(
        h, csr, rng, dinv, b, out, n);
}

// Round 6
// 177.045 us; speedup vs baseline: 2.4141x; 1.1817x over previous
//
#include <hip/hip_runtime.h>
#include <hip/hip_bf16.h>

#define F 64          // DIN == DOUT == 64
#define BK 128        // dst nodes per coarse bucket
#define PA_BLOCKS 256 // passA grid

typedef __attribute__((ext_vector_type(8))) short bf16x8;
typedef __attribute__((ext_vector_type(4))) float f32x4;

static __device__ inline short f2bf_bits(float f) {
    union { __hip_bfloat16 b; short s; } cv;
    cv.b = __float2bfloat16(f);
    return cv.s;
}

// ---------------- h = x @ W via MFMA 16x16x32 bf16 ----------------
// Block 256 = 4 waves; block covers 256 rows (4 M-tiles of 16 per wave).
// W (64x64) staged in LDS as bf16. A loaded per-lane from x (fp32 -> bf16).
// Layouts (m89/m120-verified): A[m=lane&15][k=quad*8+j]; B[k=quad*8+j][n=lane&15];
// D[row=quad*4+r][col=lane&15].
__global__ void gemm_kernel(const float* __restrict__ x, const float* __restrict__ W,
                            __hip_bfloat16* __restrict__ h, int n) {
    __shared__ short Wb[F * F];  // bf16 bits, [k][n] n-fastest
    int tid = threadIdx.x;
    for (int i = tid; i < F * F; i += 256) Wb[i] = f2bf_bits(W[i]);
    __syncthreads();
    int lane = tid & 63;
    int wv = tid >> 6;       // 0..3
    int quad = lane >> 4;    // 0..3
    int l16 = lane & 15;

    // B fragments: [kstep][nblock]
    bf16x8 bfr[2][4];
#pragma unroll
    for (int ks = 0; ks < 2; ++ks)
#pragma unroll
        for (int nb = 0; nb < 4; ++nb) {
            bf16x8 f;
#pragma unroll
            for (int j = 0; j < 8; ++j) {
                int k = ks * 32 + quad * 8 + j;
                f[j] = Wb[k * F + nb * 16 + l16];
            }
            bfr[ks][nb] = f;
        }

    int blockbase = blockIdx.x * 256;
#pragma unroll
    for (int mt = 0; mt < 4; ++mt) {
        int trow = blockbase + (wv * 4 + mt) * 16;
        int ar = trow + l16;
        bf16x8 af0, af1;
        if (ar < n) {
            const float* xr = x + (size_t)ar * F + quad * 8;
            float4 v0 = ((const float4*)xr)[0];
            float4 v1 = ((const float4*)xr)[1];
            float4 v2 = ((const float4*)(xr + 32))[0];
            float4 v3 = ((const float4*)(xr + 32))[1];
            af0[0] = f2bf_bits(v0.x); af0[1] = f2bf_bits(v0.y);
            af0[2] = f2bf_bits(v0.z); af0[3] = f2bf_bits(v0.w);
            af0[4] = f2bf_bits(v1.x); af0[5] = f2bf_bits(v1.y);
            af0[6] = f2bf_bits(v1.z); af0[7] = f2bf_bits(v1.w);
            af1[0] = f2bf_bits(v2.x); af1[1] = f2bf_bits(v2.y);
            af1[2] = f2bf_bits(v2.z); af1[3] = f2bf_bits(v2.w);
            af1[4] = f2bf_bits(v3.x); af1[5] = f2bf_bits(v3.y);
            af1[6] = f2bf_bits(v3.z); af1[7] = f2bf_bits(v3.w);
        } else {
            af0 = (bf16x8)0; af1 = (bf16x8)0;
        }
        f32x4 acc[4];
#pragma unroll
        for (int nb = 0; nb < 4; ++nb) {
            acc[nb] = (f32x4)0.f;
            acc[nb] = __builtin_amdgcn_mfma_f32_16x16x32_bf16(af0, bfr[0][nb], acc[nb], 0, 0, 0);
            acc[nb] = __builtin_amdgcn_mfma_f32_16x16x32_bf16(af1, bfr[1][nb], acc[nb], 0, 0, 0);
        }
#pragma unroll
        for (int nb = 0; nb < 4; ++nb) {
#pragma unroll
            for (int r = 0; r < 4; ++r) {
                int grow = trow + quad * 4 + r;
                if (grow < n) {
                    h[(size_t)grow * F + nb * 16 + l16] = __float2bfloat16(acc[nb][r]);
                }
            }
        }
    }
}

// ---------------- coarse histogram of col>>7 (LDS-aggregated) ----------------
__global__ void hist_kernel(const int* __restrict__ col, int* __restrict__ bcnt,
                            int e, int K) {
    __shared__ int lh[1024];
    int tid = threadIdx.x;
    for (int i = tid; i < K; i += 256) lh[i] = 0;
    __syncthreads();
    int nv = e >> 2;
    const int4* col4 = (const int4*)col;
    int stride = gridDim.x * 256;
    for (int v = blockIdx.x * 256 + tid; v < nv; v += stride) {
        int4 cs = col4[v];
        atomicAdd(&lh[cs.x >> 7], 1);
        atomicAdd(&lh[cs.y >> 7], 1);
        atomicAdd(&lh[cs.z >> 7], 1);
        atomicAdd(&lh[cs.w >> 7], 1);
    }
    if (blockIdx.x == 0 && tid == 0) {
        for (int i = nv << 2; i < e; ++i) atomicAdd(&bcnt[col[i] >> 7], 1);
    }
    __syncthreads();
    for (int i = tid; i < K; i += 256) {
        int v = lh[i];
        if (v) atomicAdd(&bcnt[i], v);
    }
}

// ---------------- single-block exclusive scan of bucket counts ----------------
__global__ void bscan_kernel(const int* __restrict__ bcnt, int* __restrict__ bstart,
                             int* __restrict__ bcursor, int K) {
    __shared__ int tmp[1024];
    int tid = threadIdx.x;
    int v = (tid < K) ? bcnt[tid] : 0;
    tmp[tid] = v;
    __syncthreads();
    for (int off = 1; off < 1024; off <<= 1) {
        int t = (tid >= off) ? tmp[tid - off] : 0;
        __syncthreads();
        tmp[tid] += t;
        __syncthreads();
    }
    if (tid < K) {
        int ex = tmp[tid] - v;
        bstart[tid] = ex;
        bcursor[tid] = ex;
        if (tid == K - 1) bstart[K] = tmp[tid];  // total == e
    }
}

// ---------------- passA: block-aggregated binning ----------------
__global__ void passA_kernel(const int* __restrict__ row, const int* __restrict__ col,
                             int* __restrict__ bcursor, unsigned* __restrict__ bin,
                             int e, int K, int chunk) {
    __shared__ int lh[1024];     // local histogram, then local cursor
    __shared__ int lbase[1024];  // reserved global base per bucket
    int tid = threadIdx.x;
    int s = blockIdx.x * chunk;
    int lim = s + chunk;
    if (lim > e) lim = e;
    for (int i = tid; i < K; i += 256) lh[i] = 0;
    __syncthreads();
    for (int i = s + tid; i < lim; i += 256) atomicAdd(&lh[col[i] >> 7], 1);
    __syncthreads();
    for (int i = tid; i < K; i += 256) {
        int c = lh[i];
        lbase[i] = c ? atomicAdd(&bcursor[i], c) : 0;
        lh[i] = 0;  // reuse as local cursor
    }
    __syncthreads();
    for (int i = s + tid; i < lim; i += 256) {
        int d = col[i];
        int bkt = d >> 7;
        int off = atomicAdd(&lh[bkt], 1);
        bin[lbase[bkt] + off] = ((unsigned)row[i] << 7) | ((unsigned)d & 127u);
    }
}

// ---------------- passB: per-bucket exact sort + metadata + h scale ----------------
__global__ void passB_kernel(const unsigned* __restrict__ bin, const int* __restrict__ bstart,
                             int* __restrict__ csr, int4* __restrict__ rng4,
                             __hip_bfloat16* __restrict__ h, int n) {
    __shared__ int lcnt[BK];
    __shared__ int lcur[BK];
    __shared__ int sc[BK];
    __shared__ float sdinv[BK];
    int tid = threadIdx.x;
    int b = blockIdx.x;
    int base = b << 7;
    if (tid < BK) lcnt[tid] = 0;
    __syncthreads();
    int s = bstart[b];
    int e2 = bstart[b + 1];
    for (int p = s + tid; p < e2; p += 256) atomicAdd(&lcnt[bin[p] & 127u], 1);
    __syncthreads();
    if (tid < BK) sc[tid] = lcnt[tid];
    __syncthreads();
    for (int off = 1; off < BK; off <<= 1) {
        int t = (tid < BK && tid >= off) ? sc[tid - off] : 0;
        __syncthreads();
        if (tid < BK) sc[tid] += t;
        __syncthreads();
    }
    if (tid < BK) {
        int cnt = lcnt[tid];
        int lstart = sc[tid] - cnt;  // exclusive
        lcur[tid] = lstart;
        int node = base + tid;
        if (node < n) {
            int gs = s + lstart;
            float di = rsqrtf((float)(cnt + 1));
            rng4[node] = make_int4(gs, gs + cnt, __float_as_int(di), 0);
            sdinv[tid] = di;
        }
    }
    __syncthreads();
    for (int p = s + tid; p < e2; p += 256) {
        unsigned u = bin[p];
        int ld = (int)(u & 127u);
        int src = (int)(u >> 7);
        int pos = s + atomicAdd(&lcur[ld], 1);
        csr[pos] = src;
    }
    int lim = BK * F;
    for (int idx = tid; idx < lim; idx += 256) {
        int node = base + (idx >> 6);
        if (node < n) {
            float di = sdinv[idx >> 6];
            size_t off = (size_t)node * F + (idx & 63);
            h[off] = __float2bfloat16(di * __bfloat162float(h[off]));
        }
    }
}

// ---------------- gather: 2 nodes per wave, bf16x2 lanes ----------------
// h rows pre-scaled by dinv[src]. 32 lanes cover a 64-channel row as dwords.
__global__ void gather_kernel(const __hip_bfloat16* __restrict__ h,
                              const int* __restrict__ csr,
                              const int4* __restrict__ rng4,
                              const float* __restrict__ b,
                              float* __restrict__ out, int n) {
    int gid = blockIdx.x * 256 + threadIdx.x;
    int i = gid >> 5;  // node; 2 nodes per wave
    if (i >= n) return;
    int cl = gid & 31; // dword index within row (2 channels)
    const __hip_bfloat162* h2 = (const __hip_bfloat162*)h;  // [n][32]
    int4 r4 = rng4[i];
    int p = r4.x, pend = r4.y;
    float di = __int_as_float(r4.z);
    float2 acc = __bfloat1622float2(h2[(size_t)i * 32 + cl]);  // self-loop
    for (; p + 4 <= pend; p += 4) {
        int s0 = csr[p];
        int s1 = csr[p + 1];
        int s2 = csr[p + 2];
        int s3 = csr[p + 3];
        float2 a0 = __bfloat1622float2(h2[(size_t)s0 * 32 + cl]);
        float2 a1 = __bfloat1622float2(h2[(size_t)s1 * 32 + cl]);
        float2 a2 = __bfloat1622float2(h2[(size_t)s2 * 32 + cl]);
        float2 a3 = __bfloat1622float2(h2[(size_t)s3 * 32 + cl]);
        acc.x += a0.x + a1.x + a2.x + a3.x;
        acc.y += a0.y + a1.y + a2.y + a3.y;
    }
    for (; p < pend; ++p) {
        float2 a = __bfloat1622float2(h2[(size_t)csr[p] * 32 + cl]);
        acc.x += a.x;
        acc.y += a.y;
    }
    float2 bb = ((const float2*)b)[cl];
    float vx = di * acc.x + bb.x;
    float vy = di * acc.y + bb.y;
    float2 res = make_float2(vx > 0.f ? vx : 0.f, vy > 0.f ? vy : 0.f);
    ((float2*)out)[(size_t)i * 32 + cl] = res;
}

extern "C" void kernel_launch(void* const* d_in, const int* in_sizes, int n_in,
                              void* d_out, int out_size, void* d_ws, size_t ws_size,
                              hipStream_t stream) {
    const float* x = (const float*)d_in[0];
    const int* ei  = (const int*)d_in[1];
    const float* W = (const float*)d_in[2];
    const float* b = (const float*)d_in[3];
    float* out = (float*)d_out;

    int n = in_sizes[0] / F;   // 100000
    int e = in_sizes[1] / 2;   // 1000000
    const int* row = ei;       // source
    const int* col = ei + e;   // target
    int K = (n + BK - 1) / BK; // 782 (<= 1024 required)

    // workspace layout (~22.4 MB)
    __hip_bfloat16* h = (__hip_bfloat16*)d_ws;                    // n*F bf16  12.8 MB
    unsigned* bin = (unsigned*)((char*)d_ws + (size_t)n * F * 2); // e          4 MB
    int* csr      = (int*)(bin + e);                              // e          4 MB
    int4* rng4    = (int4*)(csr + e);                             // n          1.6 MB
    int* bcnt     = (int*)(rng4 + n);                             // K
    int* bstart   = bcnt + 1024;                                  // K+1
    int* bcursor  = bstart + 1025;                                // K

    // 1. h = x @ W (bf16) via MFMA
    gemm_kernel<<<(n + 255) / 256, 256, 0, stream>>>(x, W, h, n);

    // 2. coarse histogram
    hipMemsetAsync(bcnt, 0, 1024 * sizeof(int), stream);
    hist_kernel<<<64, 256, 0, stream>>>(col, bcnt, e, K);

    // 3. scan bucket counts
    bscan_kernel<<<1, 1024, 0, stream>>>(bcnt, bstart, bcursor, K);

    // 4. passA: block-aggregated binning (packed 4B entries)
    int chunk = (e + PA_BLOCKS - 1) / PA_BLOCKS;
    passA_kernel<<<PA_BLOCKS, 256, 0, stream>>>(row, col, bcursor, bin, e, K, chunk);

    // 5. passB: exact per-dst sort, rng4 metadata, h *= dinv in place
    passB_kernel<<<K, 256, 0, stream>>>(bin, bstart, csr, rng4, h, n);

    // 6. gather + self-loop + bias + relu (2 nodes/wave, packed bf16x2)
    gather_kernel<<<((size_t)n * 32 + 255) / 256, 256, 0, stream>>>(
        h, csr, rng4, b, out, n);
}